// Round 9
// baseline (171.177 us; speedup 1.0000x reference)
//
#include <hip/hip_runtime.h>
#include <cmath>

#define Tn  2048
#define Cn  1024
#define Hn  64
#define BTn 16384

typedef _Float16 f16x8 __attribute__((ext_vector_type(8)));
typedef _Float16 f16x4 __attribute__((ext_vector_type(4)));
typedef _Float16 f16x2 __attribute__((ext_vector_type(2)));
typedef float    f32x4 __attribute__((ext_vector_type(4)));

#define MFMA16(a, b, c) __builtin_amdgcn_mfma_f32_16x16x32_f16(a, b, c, 0, 0, 0)

// async global->LDS, 16B per lane, wave-uniform LDS base (HW adds lane*16)
__device__ __forceinline__ void gload16(const void* g, void* l) {
    __builtin_amdgcn_global_load_lds(
        (const __attribute__((address_space(1))) void*)g,
        (__attribute__((address_space(3))) void*)l, 16, 0, 0);
}

// ---------------------------------------------------------------------------
// xcast: pure streaming fp32 -> f16 convert of x. fillBuffer-shaped: grid-
// stride, no LDS, no barriers, 8 independent load/store pairs per thread.
// 2048 blocks x 256 thr = 32 waves/CU. The harness's own fillBufferAligned
// hits 6.5 TB/s with this shape; this kernel is the decisive probe of
// whether OUR reads can stream at that rate too (R6/R7: complex kernels
// ingesting x cap at ~1 TB/s regardless of schedule).
// ---------------------------------------------------------------------------
__global__ __launch_bounds__(256) void xcast_kernel(
    const float* __restrict__ x, _Float16* __restrict__ xh)
{
    const int t = blockIdx.x * 256 + threadIdx.x;   // 524288 threads
    #pragma unroll
    for (int i = 0; i < 8; i++) {
        size_t idx = (size_t)i * 524288 + t;        // 4.19M float4 total
        float4 v = ((const float4*)x)[idx];
        f16x4 h = { (_Float16)v.x, (_Float16)v.y, (_Float16)v.z, (_Float16)v.w };
        ((f16x4*)xh)[idx] = h;
    }
}

// ---------------------------------------------------------------------------
// prep: transpose Wq|Wk|Wv (each [Cn][64] fp32) into Wt[192][Cn] f16
// ---------------------------------------------------------------------------
__global__ __launch_bounds__(256) void prep_w_kernel(
    const float* __restrict__ Wq, const float* __restrict__ Wk,
    const float* __restrict__ Wv, _Float16* __restrict__ Wt)
{
    __shared__ float ts[64][65];
    const int blk = blockIdx.x;          // 48 = 3 proj * 16 c-tiles
    const int p   = blk >> 4;
    const int c0  = (blk & 15) * 64;
    const float* __restrict__ W = (p == 0) ? Wq : (p == 1) ? Wk : Wv;
    const int tid = threadIdx.x;
    #pragma unroll
    for (int it = 0; it < 16; it++) {
        int idx = tid + it * 256;
        int c = idx >> 6, n = idx & 63;
        ts[c][n] = W[(size_t)(c0 + c) * Hn + n];
    }
    __syncthreads();
    #pragma unroll
    for (int it = 0; it < 16; it++) {
        int idx = tid + it * 256;
        int n = idx >> 6, c = idx & 63;
        Wt[(size_t)(p * 64 + n) * Cn + c0 + c] = (_Float16)ts[c][n];
    }
}

// ---------------------------------------------------------------------------
// proj, round-8/9: reads the PRE-CONVERTED f16 x (xh) -- half the staging
// bytes, and freshly L3-resident from xcast. Back to the simplest proven
// structure (R2 barrier-free K-loop): stage the whole 32x1024 f16 tile
// (64 KB) in one global_load_lds burst (8 issues/thread, source pre-
// swizzled byte ^= (row&7)<<4, LDS dest linear; read applies the same XOR
// -- the R6-verified both-sides mechanism), ONE barrier, then 16 kc steps
// of {3 Wt L2-loads + 2 LDS f16x8 reads + 6 MFMA} with no further
// barriers. Wave = (kh, wc): kh = K-half, wc = col group of 48;
// acc[2][3]; partials combined via LDS; epilogue (RoPE, vT) unchanged.
// ---------------------------------------------------------------------------
__global__ __launch_bounds__(512, 4) void proj_kernel(
    const _Float16* __restrict__ xh, const _Float16* __restrict__ Wt,
    _Float16* __restrict__ qh, _Float16* __restrict__ kh_out, _Float16* __restrict__ vT)
{
    __shared__ __align__(16) _Float16 xs[32 * 1024];   // 64 KB -> 2 blk/CU
    const int row0 = blockIdx.x * 32;
    const int tid  = threadIdx.x;
    const int wave = tid >> 6, lane = tid & 63;
    const int kh   = wave >> 2;          // K-half
    const int wc   = wave & 3;           // col group (48 cols)
    const int quad = lane >> 4, l15 = lane & 15;

    // Stage 32 rows x 1024 f16 = 64 KB via global_load_lds, one burst.
    // Linear LDS dest; global source pre-swizzled so reads can XOR.
    {
        char* lb0 = (char*)xs + wave * 1024;     // wave-uniform base
        #pragma unroll
        for (int r2 = 0; r2 < 8; r2++) {
            int lbl  = tid * 16 + r2 * 8192;     // this lane's dest byte
            int row  = lbl >> 11;                // 2048 B per row
            int colb = (lbl & 2047) ^ ((row & 7) << 4);
            gload16((const char*)(xh + (size_t)(row0 + row) * Cn) + colb,
                    lb0 + r2 * 8192);
        }
    }
    __syncthreads();                     // single barrier: tile ready

    f32x4 acc[2][3] = {};
    const _Float16* __restrict__ wb = Wt + (size_t)(wc * 48 + l15) * Cn
                                         + kh * 512 + quad * 8;
    const char* xb = (const char*)xs;

    #pragma unroll 4
    for (int kc = 0; kc < 16; kc++) {
        const int cf = (kh * 512 + kc * 32 + quad * 8) * 2;  // byte col
        f16x8 b0 = *(const f16x8*)&wb[kc * 32];
        f16x8 b1 = *(const f16x8*)&wb[16 * Cn + kc * 32];
        f16x8 b2 = *(const f16x8*)&wb[32 * Cn + kc * 32];
        int lb0 = (     l15) * 2048 + cf;
        int lb1 = (16 + l15) * 2048 + cf;
        f16x8 a0 = *(const f16x8*)(xb + (lb0 ^ ((l15 & 7) << 4)));
        f16x8 a1 = *(const f16x8*)(xb + (lb1 ^ ((l15 & 7) << 4)));
        acc[0][0] = MFMA16(a0, b0, acc[0][0]);
        acc[1][0] = MFMA16(a1, b0, acc[1][0]);
        acc[0][1] = MFMA16(a0, b1, acc[0][1]);
        acc[1][1] = MFMA16(a1, b1, acc[1][1]);
        acc[0][2] = MFMA16(a0, b2, acc[0][2]);
        acc[1][2] = MFMA16(a1, b2, acc[1][2]);
    }

    // Combine the two K-halves: waves kh=1 dump partials into LDS (reuse
    // xs), waves kh=0 add them. Lane-major f32x4 = conflict-free.
    __syncthreads();                     // everyone done reading xs
    f32x4* __restrict__ pbuf = (f32x4*)xs;      // 6*256*16B = 24.6 KB
    if (kh) {
        #pragma unroll
        for (int mt = 0; mt < 2; mt++)
            #pragma unroll
            for (int nt = 0; nt < 3; nt++)
                pbuf[(mt * 3 + nt) * 256 + wc * 64 + lane] = acc[mt][nt];
    }
    __syncthreads();
    if (kh) return;
    #pragma unroll
    for (int mt = 0; mt < 2; mt++)
        #pragma unroll
        for (int nt = 0; nt < 3; nt++)
            acc[mt][nt] += pbuf[(mt * 3 + nt) * 256 + wc * 64 + lane];

    // Epilogue (waves 0-3; wc owns cols [wc*48, wc*48+48))
    const int bidx = row0 >> 11;
    #pragma unroll
    for (int nt = 0; nt < 3; nt++) {
        const int n = wc * 48 + nt * 16 + l15;
        const int p = n >> 6;            // uniform per (wc,nt)
        const int h = n & 63;
        if (p < 2) {                     // q or k: RoPE
            _Float16* __restrict__ outb = (p == 0) ? qh : kh_out;
            const float invf = __expf(-0.2878231366242557f * (float)(h >> 1));
            #pragma unroll
            for (int mt = 0; mt < 2; mt++) {
                #pragma unroll
                for (int r = 0; r < 4; r++) {
                    int   row = row0 + mt * 16 + quad * 4 + r;
                    float val = acc[mt][nt][r];
                    float partner = __shfl_xor(val, 1, 64);
                    float ang = (float)(row & (Tn - 1)) * invf;
                    float sv, cv;
                    __sincosf(ang, &sv, &cv);
                    float res = (h & 1) ? fmaf(val, cv,  partner * sv)
                                        : fmaf(val, cv, -partner * sv);
                    if (p == 0) res *= 0.125f;
                    float resn = __shfl_xor(res, 1, 64);
                    if (!(l15 & 1)) {
                        f16x2 pk = { (_Float16)res, (_Float16)resn };
                        *(f16x2*)&outb[(size_t)row * Hn + h] = pk;
                    }
                }
            }
        } else {                         // v: store transposed vT[b][h][t]
            #pragma unroll
            for (int mt = 0; mt < 2; mt++) {
                int t = (row0 & (Tn - 1)) + mt * 16 + quad * 4;
                f16x4 pv = { (_Float16)acc[mt][nt][0], (_Float16)acc[mt][nt][1],
                             (_Float16)acc[mt][nt][2], (_Float16)acc[mt][nt][3] };
                *(f16x4*)&vT[((size_t)bidx * Hn + h) * Tn + t] = pv;
            }
        }
    }
}

// ---------------------------------------------------------------------------
// attn: barrier-free flash loop (EXACT round-2 version, the best measured).
// QT=16, STL=64, 256 thr = 4 waves; each wave processes every 4th s-tile
// with its own online-softmax state; one barrier + LDS merge at the end.
// K and vT B-frags read directly from global (L2-resident, XCD-affine via
// b = blk&7). qt permuted so each CU's resident blocks have constant work.
// ---------------------------------------------------------------------------
#define PSP 72

__global__ __launch_bounds__(256, 4) void attn_kernel(
    const _Float16* __restrict__ qh, const _Float16* __restrict__ kh,
    const _Float16* __restrict__ vT, float* __restrict__ out)
{
    __shared__ _Float16 ps[4][16 * PSP];     // wave-private P transpose
    __shared__ float ocomb[4][16][65];
    __shared__ float mlcomb[4][2][16];       // [wave][m|l][row]

    const int blk = blockIdx.x;
    const int b   = blk & 7;                 // batch == XCD affinity
    const int j   = blk >> 3;                // 0..127
    const int jm  = j & 31, g = j >> 5;      // complement permutation:
    const int qt  = (g == 0) ? (127 - jm)    // per-CU resident set sums const
                  : (g == 1) ? (64 + jm)
                  : (g == 2) ? (63 - jm) : jm;
    const int t0  = qt * 16;
    const int tid = threadIdx.x;
    const int w = tid >> 6, lane = tid & 63;
    const int quad = lane >> 4, l15 = lane & 15;

    const _Float16* __restrict__ qb = qh + (size_t)b * Tn * Hn;
    const _Float16* __restrict__ kb = kh + (size_t)b * Tn * Hn;
    const _Float16* __restrict__ vb = vT + (size_t)b * Hn * Tn;

    // Q A-frags: held in registers for the whole loop
    const f16x8 aq0 = *(const f16x8*)&qb[(size_t)(t0 + l15) * Hn +      quad * 8];
    const f16x8 aq1 = *(const f16x8*)&qb[(size_t)(t0 + l15) * Hn + 32 + quad * 8];

    float m_run[4], l_run[4];
    f32x4 oacc[4] = {};
    #pragma unroll
    for (int r = 0; r < 4; r++) { m_run[r] = -1e30f; l_run[r] = 0.0f; }

    const int nst = (t0 + 16 + 63) >> 6;
    for (int jt = w; jt < nst; jt += 4) {
        const int s0 = jt * 64;

        // K B-frags direct from global (16 rows x 64B per load instr)
        f16x8 kf[4][2];
        #pragma unroll
        for (int nt = 0; nt < 4; nt++) {
            const _Float16* kp = &kb[(size_t)(s0 + nt * 16 + l15) * Hn + quad * 8];
            kf[nt][0] = *(const f16x8*)kp;
            kf[nt][1] = *(const f16x8*)(kp + 32);
        }
        f32x4 sacc[4];
        #pragma unroll
        for (int nt = 0; nt < 4; nt++) {
            f32x4 z = {};
            z = MFMA16(aq0, kf[nt][0], z);
            z = MFMA16(aq1, kf[nt][1], z);
            sacc[nt] = z;
        }

        // vT B-frags: issue before softmax (independent), consumed by PV
        f16x8 vf[2][4];
        #pragma unroll
        for (int sc = 0; sc < 2; sc++)
            #pragma unroll
            for (int ht = 0; ht < 4; ht++)
                vf[sc][ht] = *(const f16x8*)&vb[(size_t)(ht * 16 + l15) * Tn
                                                + s0 + sc * 32 + quad * 8];

        if (jt == nst - 1) {             // causal mask: only diagonal tile
            #pragma unroll
            for (int nt = 0; nt < 4; nt++)
                #pragma unroll
                for (int r = 0; r < 4; r++) {
                    int scol = s0 + nt * 16 + l15;
                    int trow = t0 + quad * 4 + r;
                    if (scol > trow) sacc[nt][r] = -1e30f;
                }
        }

        // online softmax (rows = quad*4+r; reduce over the 16 l15 lanes)
        float pr[4][4];
        #pragma unroll
        for (int r = 0; r < 4; r++) {
            float mx = fmaxf(fmaxf(sacc[0][r], sacc[1][r]),
                             fmaxf(sacc[2][r], sacc[3][r]));
            #pragma unroll
            for (int off = 1; off < 16; off <<= 1)
                mx = fmaxf(mx, __shfl_xor(mx, off, 64));
            float mnew  = fmaxf(m_run[r], mx);
            float alpha = __expf(m_run[r] - mnew);
            m_run[r] = mnew;
            float rs = 0.0f;
            #pragma unroll
            for (int nt = 0; nt < 4; nt++) {
                float pv = __expf(sacc[nt][r] - mnew);
                pr[nt][r] = pv; rs += pv;
            }
            #pragma unroll
            for (int off = 1; off < 16; off <<= 1)
                rs += __shfl_xor(rs, off, 64);
            l_run[r] = fmaf(l_run[r], alpha, rs);
            #pragma unroll
            for (int ht = 0; ht < 4; ht++)
                oacc[ht][r] = oacc[ht][r] * alpha;
        }

        // P -> ps (wave-private; same-wave RAW, no barrier)
        #pragma unroll
        for (int nt = 0; nt < 4; nt++)
            #pragma unroll
            for (int r = 0; r < 4; r++) {
                float pv = pr[nt][r];
                float pn = __shfl_xor(pv, 1, 64);
                if (!(l15 & 1)) {
                    f16x2 pk = { (_Float16)pv, (_Float16)pn };
                    *(f16x2*)&ps[w][(quad * 4 + r) * PSP + nt * 16 + l15] = pk;
                }
            }

        // O += P V  (8 MFMA, B-frags already in registers)
        #pragma unroll
        for (int sc = 0; sc < 2; sc++) {
            f16x8 ap = *(const f16x8*)&ps[w][l15 * PSP + sc * 32 + quad * 8];
            #pragma unroll
            for (int ht = 0; ht < 4; ht++)
                oacc[ht] = MFMA16(ap, vf[sc][ht], oacc[ht]);
        }
    }

    // Write partials, barrier, merge the four waves' online-softmax states.
    #pragma unroll
    for (int r = 0; r < 4; r++) {
        #pragma unroll
        for (int ht = 0; ht < 4; ht++)
            ocomb[w][quad * 4 + r][ht * 16 + l15] = oacc[ht][r];
        if (l15 == 0) {
            mlcomb[w][0][quad * 4 + r] = m_run[r];
            mlcomb[w][1][quad * 4 + r] = l_run[r];
        }
    }
    __syncthreads();

    // wave w finalizes rows [w*4, w*4+4); 64 lanes = 64 h (coalesced)
    #pragma unroll
    for (int rp = 0; rp < 4; rp++) {
        int row = w * 4 + rp;
        float m0 = mlcomb[0][0][row], m1 = mlcomb[1][0][row];
        float m2 = mlcomb[2][0][row], m3 = mlcomb[3][0][row];
        float mm = fmaxf(fmaxf(m0, m1), fmaxf(m2, m3));
        float a0 = __expf(m0 - mm), a1 = __expf(m1 - mm);
        float a2 = __expf(m2 - mm), a3 = __expf(m3 - mm);
        float ll = mlcomb[0][1][row] * a0 + mlcomb[1][1][row] * a1
                 + mlcomb[2][1][row] * a2 + mlcomb[3][1][row] * a3;
        float ov = (ocomb[0][row][lane] * a0 + ocomb[1][row][lane] * a1
                  + ocomb[2][row][lane] * a2 + ocomb[3][row][lane] * a3) / ll;
        out[((size_t)b * Tn + t0 + row) * Hn + lane] = ov;
    }
}

extern "C" void kernel_launch(void* const* d_in, const int* in_sizes, int n_in,
                              void* d_out, int out_size, void* d_ws, size_t ws_size,
                              hipStream_t stream) {
    const float* x  = (const float*)d_in[0];
    const float* Wq = (const float*)d_in[1];
    const float* Wk = (const float*)d_in[2];
    const float* Wv = (const float*)d_in[3];

    const size_t qkvN = (size_t)BTn * Hn;
    _Float16* qh = (_Float16*)d_ws;
    _Float16* kh = qh + qkvN;
    _Float16* vT = kh + qkvN;                     // [8][64][2048] transposed
    _Float16* Wt = vT + qkvN;                     // [192][1024] f16
    _Float16* xh = Wt + (size_t)192 * Cn;         // [16384][1024] f16 (33.5 MB)

    xcast_kernel<<<2048, 256, 0, stream>>>(x, xh);
    prep_w_kernel<<<48, 256, 0, stream>>>(Wq, Wk, Wv, Wt);
    proj_kernel<<<BTn / 32, 512, 0, stream>>>(xh, Wt, qh, kh, vT);
    attn_kernel<<<1024, 256, 0, stream>>>(qh, kh, vT, (float*)d_out);
}

// Round 10
// 154.803 us; speedup vs baseline: 1.1058x; 1.1058x over previous
//
#include <hip/hip_runtime.h>
#include <cmath>

#define Tn  2048
#define Cn  1024
#define Hn  64
#define BTn 16384

typedef _Float16 f16x8 __attribute__((ext_vector_type(8)));
typedef _Float16 f16x4 __attribute__((ext_vector_type(4)));
typedef _Float16 f16x2 __attribute__((ext_vector_type(2)));
typedef float    f32x4 __attribute__((ext_vector_type(4)));

#define MFMA16(a, b, c) __builtin_amdgcn_mfma_f32_16x16x32_f16(a, b, c, 0, 0, 0)

// ---------------------------------------------------------------------------
// prep: transpose Wq|Wk|Wv (each [Cn][64] fp32) into Wt[192][Cn] f16
// ---------------------------------------------------------------------------
__global__ __launch_bounds__(256) void prep_w_kernel(
    const float* __restrict__ Wq, const float* __restrict__ Wk,
    const float* __restrict__ Wv, _Float16* __restrict__ Wt)
{
    __shared__ float ts[64][65];
    const int blk = blockIdx.x;          // 48 = 3 proj * 16 c-tiles
    const int p   = blk >> 4;
    const int c0  = (blk & 15) * 64;
    const float* __restrict__ W = (p == 0) ? Wq : (p == 1) ? Wk : Wv;
    const int tid = threadIdx.x;
    #pragma unroll
    for (int it = 0; it < 16; it++) {
        int idx = tid + it * 256;
        int c = idx >> 6, n = idx & 63;
        ts[c][n] = W[(size_t)(c0 + c) * Hn + n];
    }
    __syncthreads();
    #pragma unroll
    for (int it = 0; it < 16; it++) {
        int idx = tid + it * 256;
        int n = idx >> 6, c = idx & 63;
        Wt[(size_t)(p * 64 + n) * Cn + c0 + c] = (_Float16)ts[c][n];
    }
}

// ---------------------------------------------------------------------------
// proj, round-10. THEORY: every pipelining variant (R3 rotating regs, R6
// global_load_lds, R7 FIFO dbuf, R9 f16 input) nulled at ~43 us, and ALL
// compiled to VGPR <= 64 -- the compiler's occupancy heuristic targets the
// 8-waves/EU register tier, but occupancy here is LDS-capped at 4 waves/EU
// (64 KB -> 2 blocks/CU x 8 waves), so it buys nothing and silently
// re-sinks every prefetch (zero flight depth -> full L2 latency per kc ->
// MfmaUtil 5%). FIX: amdgpu_waves_per_eu(4,4) pins occupancy at the LDS
// bound, freeing the allocator to 128 VGPRs; re-run the R3 3-slot rotating
// register prefetch (loads for kc+3 issue under kc's MFMAs, ~110 VGPR
// live). Structure otherwise R3: 8-wave K-split blocks, 512 thr, grid 512;
// stage x (fp32) with all 16 float4 loads in flight; partials combined via
// LDS; epilogue RoPE (q pre-scaled H^-1/2) + vT[b][h][t] transpose.
// ---------------------------------------------------------------------------
#define XSP 1032

__global__ __attribute__((amdgpu_waves_per_eu(4, 4)))
__launch_bounds__(512) void proj_kernel(
    const float* __restrict__ x, const _Float16* __restrict__ Wt,
    _Float16* __restrict__ qh, _Float16* __restrict__ kh_out, _Float16* __restrict__ vT)
{
    __shared__ __align__(16) _Float16 xs[32 * XSP];   // 66 KB -> 2 blocks/CU
    const int row0 = blockIdx.x * 32;
    const int tid  = threadIdx.x;
    const int wave = tid >> 6, lane = tid & 63;
    const int kh   = wave >> 2;          // K-half
    const int wc   = wave & 3;           // col group (48 cols)
    const int quad = lane >> 4, l15 = lane & 15;

    // Stage x (32 rows x 1024 fp32 -> f16). All 16 loads in flight.
    {
        float4 xv[16];
        #pragma unroll
        for (int it = 0; it < 16; it++) {
            int idx = tid + it * 512;
            int r = idx >> 8, c4 = idx & 255;
            xv[it] = *(const float4*)&x[(size_t)(row0 + r) * Cn + c4 * 4];
        }
        #pragma unroll
        for (int it = 0; it < 16; it++) {
            int idx = tid + it * 512;
            int r = idx >> 8, c4 = idx & 255;
            f16x4 hv = { (_Float16)xv[it].x, (_Float16)xv[it].y,
                         (_Float16)xv[it].z, (_Float16)xv[it].w };
            *(f16x4*)&xs[r * XSP + c4 * 4] = hv;
        }
    }
    __syncthreads();

    f32x4 acc[2][3] = {};
    const _Float16* __restrict__ wb = Wt + (size_t)(wc * 48 + l15) * Cn
                                         + kh * 512 + quad * 8;
    const _Float16* __restrict__ xp = &xs[kh * 512 + quad * 8];

    // 3-slot rotating prefetch pipeline over 16 kc steps (K-half = 512)
    f16x8 bb[3][3], ab[3][2];
    #pragma unroll
    for (int p = 0; p < 3; p++) {
        bb[p][0] = *(const f16x8*)&wb[p * 32];
        bb[p][1] = *(const f16x8*)&wb[16 * Cn + p * 32];
        bb[p][2] = *(const f16x8*)&wb[32 * Cn + p * 32];
        ab[p][0] = *(const f16x8*)&xp[(     l15) * XSP + p * 32];
        ab[p][1] = *(const f16x8*)&xp[(16 + l15) * XSP + p * 32];
    }
    #pragma unroll
    for (int kc = 0; kc < 16; kc++) {
        const int s = kc % 3;            // static after full unroll
        acc[0][0] = MFMA16(ab[s][0], bb[s][0], acc[0][0]);
        acc[1][0] = MFMA16(ab[s][1], bb[s][0], acc[1][0]);
        acc[0][1] = MFMA16(ab[s][0], bb[s][1], acc[0][1]);
        acc[1][1] = MFMA16(ab[s][1], bb[s][1], acc[1][1]);
        acc[0][2] = MFMA16(ab[s][0], bb[s][2], acc[0][2]);
        acc[1][2] = MFMA16(ab[s][1], bb[s][2], acc[1][2]);
        if (kc + 3 < 16) {
            const int kn = (kc + 3) * 32;
            bb[s][0] = *(const f16x8*)&wb[kn];
            bb[s][1] = *(const f16x8*)&wb[16 * Cn + kn];
            bb[s][2] = *(const f16x8*)&wb[32 * Cn + kn];
            ab[s][0] = *(const f16x8*)&xp[(     l15) * XSP + kn];
            ab[s][1] = *(const f16x8*)&xp[(16 + l15) * XSP + kn];
        }
    }

    // Combine the two K-halves: waves 4-7 dump partials into LDS (reuse xs),
    // waves 0-3 add them. Lane-major f32x4 layout = conflict-free.
    __syncthreads();                     // everyone done reading xs
    f32x4* __restrict__ pbuf = (f32x4*)xs;   // 6*256*16B = 24.6 KB
    if (kh) {
        #pragma unroll
        for (int mt = 0; mt < 2; mt++)
            #pragma unroll
            for (int nt = 0; nt < 3; nt++)
                pbuf[(mt * 3 + nt) * 256 + wc * 64 + lane] = acc[mt][nt];
    }
    __syncthreads();
    if (kh) return;
    #pragma unroll
    for (int mt = 0; mt < 2; mt++)
        #pragma unroll
        for (int nt = 0; nt < 3; nt++)
            acc[mt][nt] += pbuf[(mt * 3 + nt) * 256 + wc * 64 + lane];

    // Epilogue (waves 0-3; wc owns cols [wc*48, wc*48+48))
    const int bidx = row0 >> 11;
    #pragma unroll
    for (int nt = 0; nt < 3; nt++) {
        const int n = wc * 48 + nt * 16 + l15;
        const int p = n >> 6;            // uniform per (wc,nt)
        const int h = n & 63;
        if (p < 2) {                     // q or k: RoPE
            _Float16* __restrict__ outb = (p == 0) ? qh : kh_out;
            const float invf = __expf(-0.2878231366242557f * (float)(h >> 1));
            #pragma unroll
            for (int mt = 0; mt < 2; mt++) {
                #pragma unroll
                for (int r = 0; r < 4; r++) {
                    int   row = row0 + mt * 16 + quad * 4 + r;
                    float val = acc[mt][nt][r];
                    float partner = __shfl_xor(val, 1, 64);
                    float ang = (float)(row & (Tn - 1)) * invf;
                    float sv, cv;
                    __sincosf(ang, &sv, &cv);
                    float res = (h & 1) ? fmaf(val, cv,  partner * sv)
                                        : fmaf(val, cv, -partner * sv);
                    if (p == 0) res *= 0.125f;
                    float resn = __shfl_xor(res, 1, 64);
                    if (!(l15 & 1)) {
                        f16x2 pk = { (_Float16)res, (_Float16)resn };
                        *(f16x2*)&outb[(size_t)row * Hn + h] = pk;
                    }
                }
            }
        } else {                         // v: store transposed vT[b][h][t]
            #pragma unroll
            for (int mt = 0; mt < 2; mt++) {
                int t = (row0 & (Tn - 1)) + mt * 16 + quad * 4;
                f16x4 pv = { (_Float16)acc[mt][nt][0], (_Float16)acc[mt][nt][1],
                             (_Float16)acc[mt][nt][2], (_Float16)acc[mt][nt][3] };
                *(f16x4*)&vT[((size_t)bidx * Hn + h) * Tn + t] = pv;
            }
        }
    }
}

// ---------------------------------------------------------------------------
// attn: barrier-free flash loop (EXACT round-2 version, the best measured).
// QT=16, STL=64, 256 thr = 4 waves; each wave processes every 4th s-tile
// with its own online-softmax state; one barrier + LDS merge at the end.
// K and vT B-frags read directly from global (L2-resident, XCD-affine via
// b = blk&7). qt permuted so each CU's resident blocks have constant work.
// Untouched this round: single-variable experiment on proj.
// ---------------------------------------------------------------------------
#define PSP 72

__global__ __launch_bounds__(256, 4) void attn_kernel(
    const _Float16* __restrict__ qh, const _Float16* __restrict__ kh,
    const _Float16* __restrict__ vT, float* __restrict__ out)
{
    __shared__ _Float16 ps[4][16 * PSP];     // wave-private P transpose
    __shared__ float ocomb[4][16][65];
    __shared__ float mlcomb[4][2][16];       // [wave][m|l][row]

    const int blk = blockIdx.x;
    const int b   = blk & 7;                 // batch == XCD affinity
    const int j   = blk >> 3;                // 0..127
    const int jm  = j & 31, g = j >> 5;      // complement permutation:
    const int qt  = (g == 0) ? (127 - jm)    // per-CU resident set sums const
                  : (g == 1) ? (64 + jm)
                  : (g == 2) ? (63 - jm) : jm;
    const int t0  = qt * 16;
    const int tid = threadIdx.x;
    const int w = tid >> 6, lane = tid & 63;
    const int quad = lane >> 4, l15 = lane & 15;

    const _Float16* __restrict__ qb = qh + (size_t)b * Tn * Hn;
    const _Float16* __restrict__ kb = kh + (size_t)b * Tn * Hn;
    const _Float16* __restrict__ vb = vT + (size_t)b * Hn * Tn;

    // Q A-frags: held in registers for the whole loop
    const f16x8 aq0 = *(const f16x8*)&qb[(size_t)(t0 + l15) * Hn +      quad * 8];
    const f16x8 aq1 = *(const f16x8*)&qb[(size_t)(t0 + l15) * Hn + 32 + quad * 8];

    float m_run[4], l_run[4];
    f32x4 oacc[4] = {};
    #pragma unroll
    for (int r = 0; r < 4; r++) { m_run[r] = -1e30f; l_run[r] = 0.0f; }

    const int nst = (t0 + 16 + 63) >> 6;
    for (int jt = w; jt < nst; jt += 4) {
        const int s0 = jt * 64;

        // K B-frags direct from global (16 rows x 64B per load instr)
        f16x8 kf[4][2];
        #pragma unroll
        for (int nt = 0; nt < 4; nt++) {
            const _Float16* kp = &kb[(size_t)(s0 + nt * 16 + l15) * Hn + quad * 8];
            kf[nt][0] = *(const f16x8*)kp;
            kf[nt][1] = *(const f16x8*)(kp + 32);
        }
        f32x4 sacc[4];
        #pragma unroll
        for (int nt = 0; nt < 4; nt++) {
            f32x4 z = {};
            z = MFMA16(aq0, kf[nt][0], z);
            z = MFMA16(aq1, kf[nt][1], z);
            sacc[nt] = z;
        }

        // vT B-frags: issue before softmax (independent), consumed by PV
        f16x8 vf[2][4];
        #pragma unroll
        for (int sc = 0; sc < 2; sc++)
            #pragma unroll
            for (int ht = 0; ht < 4; ht++)
                vf[sc][ht] = *(const f16x8*)&vb[(size_t)(ht * 16 + l15) * Tn
                                                + s0 + sc * 32 + quad * 8];

        if (jt == nst - 1) {             // causal mask: only diagonal tile
            #pragma unroll
            for (int nt = 0; nt < 4; nt++)
                #pragma unroll
                for (int r = 0; r < 4; r++) {
                    int scol = s0 + nt * 16 + l15;
                    int trow = t0 + quad * 4 + r;
                    if (scol > trow) sacc[nt][r] = -1e30f;
                }
        }

        // online softmax (rows = quad*4+r; reduce over the 16 l15 lanes)
        float pr[4][4];
        #pragma unroll
        for (int r = 0; r < 4; r++) {
            float mx = fmaxf(fmaxf(sacc[0][r], sacc[1][r]),
                             fmaxf(sacc[2][r], sacc[3][r]));
            #pragma unroll
            for (int off = 1; off < 16; off <<= 1)
                mx = fmaxf(mx, __shfl_xor(mx, off, 64));
            float mnew  = fmaxf(m_run[r], mx);
            float alpha = __expf(m_run[r] - mnew);
            m_run[r] = mnew;
            float rs = 0.0f;
            #pragma unroll
            for (int nt = 0; nt < 4; nt++) {
                float pv = __expf(sacc[nt][r] - mnew);
                pr[nt][r] = pv; rs += pv;
            }
            #pragma unroll
            for (int off = 1; off < 16; off <<= 1)
                rs += __shfl_xor(rs, off, 64);
            l_run[r] = fmaf(l_run[r], alpha, rs);
            #pragma unroll
            for (int ht = 0; ht < 4; ht++)
                oacc[ht][r] = oacc[ht][r] * alpha;
        }

        // P -> ps (wave-private; same-wave RAW, no barrier)
        #pragma unroll
        for (int nt = 0; nt < 4; nt++)
            #pragma unroll
            for (int r = 0; r < 4; r++) {
                float pv = pr[nt][r];
                float pn = __shfl_xor(pv, 1, 64);
                if (!(l15 & 1)) {
                    f16x2 pk = { (_Float16)pv, (_Float16)pn };
                    *(f16x2*)&ps[w][(quad * 4 + r) * PSP + nt * 16 + l15] = pk;
                }
            }

        // O += P V  (8 MFMA, B-frags already in registers)
        #pragma unroll
        for (int sc = 0; sc < 2; sc++) {
            f16x8 ap = *(const f16x8*)&ps[w][l15 * PSP + sc * 32 + quad * 8];
            #pragma unroll
            for (int ht = 0; ht < 4; ht++)
                oacc[ht] = MFMA16(ap, vf[sc][ht], oacc[ht]);
        }
    }

    // Write partials, barrier, merge the four waves' online-softmax states.
    #pragma unroll
    for (int r = 0; r < 4; r++) {
        #pragma unroll
        for (int ht = 0; ht < 4; ht++)
            ocomb[w][quad * 4 + r][ht * 16 + l15] = oacc[ht][r];
        if (l15 == 0) {
            mlcomb[w][0][quad * 4 + r] = m_run[r];
            mlcomb[w][1][quad * 4 + r] = l_run[r];
        }
    }
    __syncthreads();

    // wave w finalizes rows [w*4, w*4+4); 64 lanes = 64 h (coalesced)
    #pragma unroll
    for (int rp = 0; rp < 4; rp++) {
        int row = w * 4 + rp;
        float m0 = mlcomb[0][0][row], m1 = mlcomb[1][0][row];
        float m2 = mlcomb[2][0][row], m3 = mlcomb[3][0][row];
        float mm = fmaxf(fmaxf(m0, m1), fmaxf(m2, m3));
        float a0 = __expf(m0 - mm), a1 = __expf(m1 - mm);
        float a2 = __expf(m2 - mm), a3 = __expf(m3 - mm);
        float ll = mlcomb[0][1][row] * a0 + mlcomb[1][1][row] * a1
                 + mlcomb[2][1][row] * a2 + mlcomb[3][1][row] * a3;
        float ov = (ocomb[0][row][lane] * a0 + ocomb[1][row][lane] * a1
                  + ocomb[2][row][lane] * a2 + ocomb[3][row][lane] * a3) / ll;
        out[((size_t)b * Tn + t0 + row) * Hn + lane] = ov;
    }
}

extern "C" void kernel_launch(void* const* d_in, const int* in_sizes, int n_in,
                              void* d_out, int out_size, void* d_ws, size_t ws_size,
                              hipStream_t stream) {
    const float* x  = (const float*)d_in[0];
    const float* Wq = (const float*)d_in[1];
    const float* Wk = (const float*)d_in[2];
    const float* Wv = (const float*)d_in[3];

    const size_t qkvN = (size_t)BTn * Hn;
    _Float16* qh = (_Float16*)d_ws;
    _Float16* kh = qh + qkvN;
    _Float16* vT = kh + qkvN;                     // [8][64][2048] transposed
    _Float16* Wt = vT + qkvN;                     // [192][1024] f16

    prep_w_kernel<<<48, 256, 0, stream>>>(Wq, Wk, Wv, Wt);
    proj_kernel<<<BTn / 32, 512, 0, stream>>>(x, Wt, qh, kh, vT);
    attn_kernel<<<1024, 256, 0, stream>>>(qh, kh, vT, (float*)d_out);
}